// Round 5
// baseline (467.180 us; speedup 1.0000x reference)
//
#include <hip/hip_runtime.h>

#define B_  128
#define N_  32
#define L_  36
#define DS  512
#define DV  1024
#define H_  512
#define P_  496
#define R_  63488      // B_*P_

typedef __attribute__((ext_vector_type(8))) short bf16x8;
typedef __attribute__((ext_vector_type(4))) float f32x4;

__device__ __forceinline__ ushort f2bf(float x){
  unsigned u = __builtin_bit_cast(unsigned, x);
  return (ushort)((u + 0x7FFFu + ((u >> 16) & 1u)) >> 16);
}
__device__ __forceinline__ float bf2f(ushort u){
  unsigned v = ((unsigned)u) << 16;
  return __builtin_bit_cast(float, v);
}

__device__ __forceinline__ void gload16(const void* g, void* l){
  __builtin_amdgcn_global_load_lds((const __attribute__((address_space(1))) unsigned*)g,
                                   (__attribute__((address_space(3))) unsigned*)l, 16, 0, 0);
}

// ---------- wave helpers ----------
__device__ __forceinline__ float wave_sum(float v){
  #pragma unroll
  for (int m = 32; m >= 1; m >>= 1) v += __shfl_xor(v, m);
  return v;
}
__device__ __forceinline__ float wave_max(float v){
  #pragma unroll
  for (int m = 32; m >= 1; m >>= 1) v = fmaxf(v, __shfl_xor(v, m));
  return v;
}

// ---------- merged setup: pair table + mask counts + loss zero ----------
__global__ void setup_kernel(const float* __restrict__ sm, const float* __restrict__ im,
                             float* cnt_s, float* cnt_i, int* iu, int* ju, float* loss){
  int t = threadIdx.x;  // 512
  if (t < P_){
    int i = 0, rem = t, cnt = N_ - 1;
    while (rem >= cnt){ rem -= cnt; ++i; --cnt; }
    iu[t] = i; ju[t] = i + 1 + rem;
  }
  if (t < B_){
    float s = 0.f;
    for (int n = 0; n < N_; ++n) s += sm[t*N_ + n];
    cnt_s[t] = s;
  } else if (t < 2*B_){
    int j = t - B_;
    float s = 0.f;
    for (int l = 0; l < L_; ++l) s += im[j*L_ + l];
    cnt_i[j] = s;
  }
  if (t == 0) loss[0] = 0.f;
}

// ---------- merged conversions: span + img -> bf16 ----------
#define SPAN_F4 524288        // 4096*512/4
#define IMG_F4  1179648       // 128*36*1024/4
__global__ void conv_all(const float* __restrict__ span, const float* __restrict__ img,
                         ushort* __restrict__ spbf, ushort* __restrict__ imgbf){
  int idx = blockIdx.x * 256 + threadIdx.x;
  const float* src; ushort* dst; int k;
  if (idx < SPAN_F4){ src = span; dst = spbf; k = idx; }
  else              { src = img;  dst = imgbf; k = idx - SPAN_F4; }
  float4 v = *(const float4*)&src[(size_t)k * 4];
  ushort4 o; o.x = f2bf(v.x); o.y = f2bf(v.y); o.z = f2bf(v.z); o.w = f2bf(v.w);
  *(ushort4*)&dst[(size_t)k * 4] = o;
}

// ---------- merged weight transposes (Wg, W1 x3, W2) ----------
__global__ void transpose_all(const float* __restrict__ Wg, const float* __restrict__ W1,
                              const float* __restrict__ W2, ushort* __restrict__ WgT,
                              ushort* __restrict__ UVBT, ushort* __restrict__ W1cT,
                              ushort* __restrict__ W2T){
  const int z = blockIdx.z;
  const float* src; ushort* dst; int N;
  if      (z == 0){ src = Wg;            dst = WgT;            N = 1024; }
  else if (z == 1){ src = W1;            dst = UVBT;           N = 512;  }
  else if (z == 2){ src = W1 + 512*512;  dst = UVBT + 512*512; N = 512;  }
  else if (z == 3){ src = W1 + 1024*512; dst = W1cT;           N = 512;  }
  else            { src = W2;            dst = W2T;            N = 512;  }
  if (blockIdx.x * 32 >= N) return;
  __shared__ float tile[32][33];
  int n0 = blockIdx.x * 32, k0 = blockIdx.y * 32;
  int x = threadIdx.x, y = threadIdx.y;   // 32 x 8
  #pragma unroll
  for (int i = 0; i < 4; ++i) tile[y + 8*i][x] = src[(k0 + y + 8*i) * N + n0 + x];
  __syncthreads();
  #pragma unroll
  for (int i = 0; i < 4; ++i) dst[(n0 + y + 8*i) * 512 + k0 + x] = f2bf(tile[x][y + 8*i]);
}

// Z[r][k] = span[b,i,k]*span[b,j,k] bf16; also text[r] = b3
__global__ void make_z(const float* __restrict__ span, const int* __restrict__ iu,
                       const int* __restrict__ ju, const float* __restrict__ b3,
                       ushort* __restrict__ Z, float* __restrict__ text){
  int idx = blockIdx.x * 256 + threadIdx.x;    // 4 elems each
  if (idx < R_) text[idx] = b3[0];
  int r = idx >> 7;
  int k = (idx & 127) << 2;
  int b = r / P_, p = r - b * P_;
  float4 x = *(const float4*)&span[(b * N_ + iu[p]) * DS + k];
  float4 y = *(const float4*)&span[(b * N_ + ju[p]) * DS + k];
  ushort4 o;
  o.x = f2bf(x.x * y.x); o.y = f2bf(x.y * y.y); o.z = f2bf(x.z * y.z); o.w = f2bf(x.w * y.w);
  *(ushort4*)&Z[(size_t)r * 512 + k] = o;
}

// ---------- shared bf16 MFMA mainloop (LDS-staged; used by small GEMMs) ----------
__device__ __forceinline__ void mma_mainloop(const ushort* __restrict__ A,
                                             const ushort* __restrict__ BT,
                                             size_t m0, int n0,
                                             ushort* sA, ushort* sB, f32x4 acc[4][4]){
  const int tid = threadIdx.x, wid = tid >> 6, lane = tid & 63;
  const int wm = (wid >> 1) * 64, wn = (wid & 1) * 64;
  const int quad = lane >> 4, fm = lane & 15;
  const char* gA = (const char*)A + (m0 + (size_t)(wid * 32 + (lane >> 2))) * 1024 + (lane & 3) * 16;
  const char* gB = (const char*)BT + ((size_t)n0 + wid * 32 + (lane >> 2)) * 1024 + (lane & 3) * 16;
  ushort* lA = sA + wid * 32 * 32;
  ushort* lB = sB + wid * 32 * 32;
  #pragma unroll 1
  for (int ks = 0; ks < 16; ++ks){
    gload16(gA,             lA);
    gload16(gA + 16 * 1024, lA + 16 * 32);
    gload16(gB,             lB);
    gload16(gB + 16 * 1024, lB + 16 * 32);
    __syncthreads();
    bf16x8 af[4], bg[4];
    #pragma unroll
    for (int i = 0; i < 4; ++i){
      af[i] = *(const bf16x8*)&sA[(wm + i * 16 + fm) * 32 + quad * 8];
      bg[i] = *(const bf16x8*)&sB[(wn + i * 16 + fm) * 32 + quad * 8];
    }
    #pragma unroll
    for (int i = 0; i < 4; ++i)
      #pragma unroll
      for (int j = 0; j < 4; ++j)
        acc[i][j] = __builtin_amdgcn_mfma_f32_16x16x32_bf16(af[i], bg[j], acc[i][j], 0, 0, 0);
    __syncthreads();
    gA += 64; gB += 64;
  }
}

// UV = span_bf @ [W1a|W1b]  (4096 x 1024), bf16 out
__global__ __launch_bounds__(256) void gemm_uv(const ushort* __restrict__ A,
                                               const ushort* __restrict__ BT,
                                               ushort* __restrict__ C){
  __shared__ ushort sA[4096], sB[4096];
  f32x4 acc[4][4] = {};
  size_t m0 = (size_t)blockIdx.y * 128; int n0 = blockIdx.x * 128;
  mma_mainloop(A, BT, m0, n0, sA, sB, acc);
  const int tid = threadIdx.x, wid = tid >> 6, lane = tid & 63;
  const int wm = (wid >> 1) * 64, wn = (wid & 1) * 64, quad = lane >> 4, fm = lane & 15;
  #pragma unroll
  for (int i = 0; i < 4; ++i)
    #pragma unroll
    for (int r = 0; r < 4; ++r){
      size_t row = m0 + wm + i * 16 + quad * 4 + r;
      #pragma unroll
      for (int j = 0; j < 4; ++j){
        int col = n0 + wn + j * 16 + fm;
        C[row * 1024 + col] = f2bf(acc[i][j][r]);
      }
    }
}

// SGbf = span_bf @ Wg  (4096 x 1024), bf16 out
__global__ __launch_bounds__(256) void gemm_sgbf(const ushort* __restrict__ A,
                                                 const ushort* __restrict__ BT,
                                                 ushort* __restrict__ C){
  __shared__ ushort sA[4096], sB[4096];
  f32x4 acc[4][4] = {};
  size_t m0 = (size_t)blockIdx.y * 128; int n0 = blockIdx.x * 128;
  mma_mainloop(A, BT, m0, n0, sA, sB, acc);
  const int tid = threadIdx.x, wid = tid >> 6, lane = tid & 63;
  const int wm = (wid >> 1) * 64, wn = (wid & 1) * 64, quad = lane >> 4, fm = lane & 15;
  #pragma unroll
  for (int i = 0; i < 4; ++i)
    #pragma unroll
    for (int r = 0; r < 4; ++r){
      size_t row = m0 + wm + i * 16 + quad * 4 + r;
      #pragma unroll
      for (int j = 0; j < 4; ++j){
        int col = n0 + wn + j * 16 + fm;
        C[row * 1024 + col] = f2bf(acc[i][j][r]);
      }
    }
}

// M[b] = SGbf[b] @ imgbf[b]^T; also Msum[b,:] and Mtot[b]
__global__ __launch_bounds__(256) void batched_m_mfma(const ushort* __restrict__ SGbf,
                                                      const ushort* __restrict__ imgbf,
                                                      const float* __restrict__ sm,
                                                      float* __restrict__ Mout,
                                                      float* __restrict__ Msum,
                                                      float* __restrict__ Mtot){
  const int b = blockIdx.x;
  const int tid = threadIdx.x, wid = tid >> 6, lane = tid & 63;
  const int quad = lane >> 4, fm = lane & 15;
  __shared__ float red[4][32][48];
  __shared__ float shr[4];
  f32x4 acc[2][3] = {};
  const int wk = wid * 256;              // K-quarter base
  const ushort* Ab = SGbf + (size_t)b * 32 * 1024;
  const ushort* Bb = imgbf + (size_t)b * 36 * 1024;
  #pragma unroll
  for (int ks = 0; ks < 8; ++ks){
    const int k = wk + ks * 32 + quad * 8;
    bf16x8 af[2], bg[3];
    af[0] = *(const bf16x8*)&Ab[(0*16 + fm) * 1024 + k];
    af[1] = *(const bf16x8*)&Ab[(1*16 + fm) * 1024 + k];
    bg[0] = *(const bf16x8*)&Bb[(0*16 + fm) * 1024 + k];
    bg[1] = *(const bf16x8*)&Bb[(1*16 + fm) * 1024 + k];
    bg[2] = *(const bf16x8*)&Bb[(2*16 + fm) * 1024 + k];  // rows 36..47 slack
    #pragma unroll
    for (int i = 0; i < 2; ++i)
      #pragma unroll
      for (int j = 0; j < 3; ++j)
        acc[i][j] = __builtin_amdgcn_mfma_f32_16x16x32_bf16(af[i], bg[j], acc[i][j], 0, 0, 0);
  }
  #pragma unroll
  for (int i = 0; i < 2; ++i)
    #pragma unroll
    for (int j = 0; j < 3; ++j)
      #pragma unroll
      for (int r = 0; r < 4; ++r)
        red[wid][i*16 + quad*4 + r][j*16 + fm] = acc[i][j][r];
  __syncthreads();
  float tot = 0.f;
  #pragma unroll
  for (int q = 0; q < 5; ++q){
    int out = tid + 256 * q;
    if (out < N_*L_){
      int n = out / L_, l = out - n * L_;
      float v = red[0][n][l] + red[1][n][l] + red[2][n][l] + red[3][n][l];
      Mout[b * (N_*L_) + out] = v;
      tot += v;
    }
  }
  tot = wave_sum(tot);
  if (lane == 0) shr[wid] = tot;
  __syncthreads();
  if (tid == 0) Mtot[b] = shr[0] + shr[1] + shr[2] + shr[3];
  if (tid < L_){
    float s = 0.f;
    for (int n = 0; n < N_; ++n){
      float mv = red[0][n][tid] + red[1][n][tid] + red[2][n][tid] + red[3][n][tid];
      s += mv * sm[b*N_ + n];
    }
    Msum[b*L_ + tid] = s;
  }
}

__global__ void sent_kernel(const float* __restrict__ Msum, const float* __restrict__ im,
                            const float* __restrict__ cnt_s, const float* __restrict__ cnt_i,
                            const float* __restrict__ Mtot, float* __restrict__ sent){
  const int i = blockIdx.x, j = threadIdx.x;  // 128 threads
  float s = 0.f;
  for (int l = 0; l < L_; ++l) s += Msum[i*L_ + l] * im[j*L_ + l];
  const float d = cnt_s[i] * cnt_i[j];
  sent[i*B_ + j] = (d != 0.f) ? (s / d) : (Mtot[i] * (1.f/(float)(N_*L_)));
}

// per-row/col logsumexp + direct loss accumulation (atomic)
__global__ void lse_loss(const float* __restrict__ sent, float* __restrict__ out){
  const int i = blockIdx.x, t = threadIdx.x;  // 128 threads = 2 waves
  const int wid = t >> 6, lane = t & 63;
  __shared__ float sh[2];
  const float vr = sent[i*B_ + t];
  const float vc = sent[t*B_ + i];

  float m = wave_max(vr);
  if (lane == 0) sh[wid] = m;
  __syncthreads();
  const float mr = fmaxf(sh[0], sh[1]);
  __syncthreads();
  float e = wave_sum(expf(vr - mr));
  if (lane == 0) sh[wid] = e;
  __syncthreads();
  const float ser = sh[0] + sh[1];
  __syncthreads();
  float rs = wave_sum(vr);
  if (lane == 0) sh[wid] = rs;
  __syncthreads();
  const float rst = sh[0] + sh[1];
  __syncthreads();
  float mc0 = wave_max(vc);
  if (lane == 0) sh[wid] = mc0;
  __syncthreads();
  const float mc = fmaxf(sh[0], sh[1]);
  __syncthreads();
  float ec = wave_sum(expf(vc - mc));
  if (lane == 0) sh[wid] = ec;
  __syncthreads();
  const float sec = sh[0] + sh[1];
  if (t == 0){
    float contrib = (mr + logf(ser)) + (mc + logf(sec)) - 2.f * rst / (float)B_;
    atomicAdd(out, contrib);
  }
}

// ---------- FUSED text path, barrier-free K-loops ----------
// Fragments loaded directly from global (L2-hot); sH holds the h1 tile.
__global__ __launch_bounds__(256, 2) void gemm_zh(const ushort* __restrict__ Z,
                                                  const ushort* __restrict__ W1cT,
                                                  const ushort* __restrict__ W2T,
                                                  const ushort* __restrict__ UV,
                                                  const float* __restrict__ b1,
                                                  const float* __restrict__ b2,
                                                  const float* __restrict__ W3,
                                                  const int* __restrict__ iu,
                                                  const int* __restrict__ ju,
                                                  float* __restrict__ text){
  __shared__ ushort sH[64 * 520];    // h1 tile, stride 520
  const int tid = threadIdx.x, wid = tid >> 6, lane = tid & 63;
  const int wm = (wid >> 1) * 32, wn = (wid & 1) * 64;
  const int quad = lane >> 4, fm = lane & 15;
  const int m0 = blockIdx.x * 64;

  int grow[8], uoff[8], voff[8];
  #pragma unroll
  for (int i = 0; i < 2; ++i)
    #pragma unroll
    for (int r = 0; r < 4; ++r){
      int row = m0 + wm + i * 16 + quad * 4 + r;
      grow[i*4+r] = row;
      int b = row / P_, p = row - b * P_;
      uoff[i*4+r] = (b * N_ + iu[p]) * 1024;
      voff[i*4+r] = (b * N_ + ju[p]) * 1024 + 512;
    }

  // ---- phase 1: h1 = relu(Z@W1c + U + V + b1) -> sH ----
  const ushort* Arow = Z + (size_t)(m0 + wm + fm) * 512 + quad * 8;
  for (int n0 = 0; n0 < 512; n0 += 128){
    f32x4 acc[2][4] = {};
    const ushort* Brow = W1cT + (size_t)(n0 + wn + fm) * 512 + quad * 8;
    #pragma unroll 4
    for (int ks = 0; ks < 16; ++ks){
      bf16x8 af[2], bg[4];
      af[0] = *(const bf16x8*)(Arow + ks * 32);
      af[1] = *(const bf16x8*)(Arow + 16 * 512 + ks * 32);
      bg[0] = *(const bf16x8*)(Brow + ks * 32);
      bg[1] = *(const bf16x8*)(Brow + 16 * 512 + ks * 32);
      bg[2] = *(const bf16x8*)(Brow + 32 * 512 + ks * 32);
      bg[3] = *(const bf16x8*)(Brow + 48 * 512 + ks * 32);
      #pragma unroll
      for (int i = 0; i < 2; ++i)
        #pragma unroll
        for (int j = 0; j < 4; ++j)
          acc[i][j] = __builtin_amdgcn_mfma_f32_16x16x32_bf16(af[i], bg[j], acc[i][j], 0, 0, 0);
    }
    #pragma unroll
    for (int i = 0; i < 2; ++i)
      #pragma unroll
      for (int r = 0; r < 4; ++r){
        const int e = i*4 + r;
        const int lrow = wm + i * 16 + quad * 4 + r;
        #pragma unroll
        for (int j = 0; j < 4; ++j){
          int col = n0 + wn + j * 16 + fm;
          float h = acc[i][j][r] + bf2f(UV[uoff[e] + col]) + bf2f(UV[voff[e] + col]) + b1[col];
          sH[lrow * 520 + col] = f2bf(fmaxf(h, 0.f));
        }
      }
  }
  __syncthreads();

  // ---- phase 2: text += relu(sH @ W2 + b2) . W3 ----
  float srow[8] = {};
  for (int n0 = 0; n0 < 512; n0 += 128){
    f32x4 acc[2][4] = {};
    const ushort* Brow = W2T + (size_t)(n0 + wn + fm) * 512 + quad * 8;
    #pragma unroll 4
    for (int ks = 0; ks < 16; ++ks){
      bf16x8 af[2], bg[4];
      af[0] = *(const bf16x8*)&sH[(wm + 0*16 + fm) * 520 + ks * 32 + quad * 8];
      af[1] = *(const bf16x8*)&sH[(wm + 1*16 + fm) * 520 + ks * 32 + quad * 8];
      bg[0] = *(const bf16x8*)(Brow + ks * 32);
      bg[1] = *(const bf16x8*)(Brow + 16 * 512 + ks * 32);
      bg[2] = *(const bf16x8*)(Brow + 32 * 512 + ks * 32);
      bg[3] = *(const bf16x8*)(Brow + 48 * 512 + ks * 32);
      #pragma unroll
      for (int i = 0; i < 2; ++i)
        #pragma unroll
        for (int j = 0; j < 4; ++j)
          acc[i][j] = __builtin_amdgcn_mfma_f32_16x16x32_bf16(af[i], bg[j], acc[i][j], 0, 0, 0);
    }
    #pragma unroll
    for (int i = 0; i < 2; ++i)
      #pragma unroll
      for (int r = 0; r < 4; ++r){
        float s = srow[i*4+r];
        #pragma unroll
        for (int j = 0; j < 4; ++j){
          int col = n0 + wn + j * 16 + fm;
          float h = fmaxf(acc[i][j][r] + b2[col], 0.f);
          s = fmaf(h, W3[col], s);
        }
        srow[i*4+r] = s;
      }
  }
  #pragma unroll
  for (int e = 0; e < 8; ++e){
    float s = srow[e];
    s += __shfl_xor(s, 1); s += __shfl_xor(s, 2); s += __shfl_xor(s, 4); s += __shfl_xor(s, 8);
    if (fm == 0) atomicAdd(&text[grow[e]], s);
  }
}

extern "C" void kernel_launch(void* const* d_in, const int* in_sizes, int n_in,
                              void* d_out, int out_size, void* d_ws, size_t ws_size,
                              hipStream_t stream) {
  const float* span = (const float*)d_in[0];
  const float* img  = (const float*)d_in[1];
  const float* sm   = (const float*)d_in[2];
  const float* im   = (const float*)d_in[3];
  const float* Wg   = (const float*)d_in[4];
  const float* W1   = (const float*)d_in[5];
  const float* b1   = (const float*)d_in[6];
  const float* W2   = (const float*)d_in[7];
  const float* b2   = (const float*)d_in[8];
  const float* W3   = (const float*)d_in[9];
  const float* b3   = (const float*)d_in[10];

  float* out  = (float*)d_out;
  float* loss = out;
  float* Mout = out + 1;
  float* text = out + 1 + B_*N_*L_;

  ushort* wsu  = (ushort*)d_ws;
  ushort* Zbf  = wsu;                          // R_*512
  ushort* UVbf = Zbf + (size_t)R_*512;         // 4096*1024
  ushort* SGbf = UVbf + 4096*1024;             // 4096*1024
  ushort* spbf = SGbf + 4096*1024;             // 4096*512
  ushort* imgbf= spbf + 4096*512;              // 128*36*1024 + 12*1024 slack
  ushort* UVBT = imgbf + (size_t)(B_*L_ + 12)*1024; // 1024*512
  ushort* W1cT = UVBT + 1024*512;              // 512*512
  ushort* W2T  = W1cT + 512*512;               // 512*512
  ushort* WgT  = W2T + 512*512;                // 1024*512
  float* Msum  = (float*)(WgT + 1024*512);     // 4608
  float* Mtot  = Msum + B_*L_;
  float* cnt_s = Mtot + B_;
  float* cnt_i = cnt_s + B_;
  float* sent  = cnt_i + B_;                   // 16384
  int*   iu    = (int*)(sent + B_*B_);         // 496
  int*   ju    = iu + P_;                      // 496

  setup_kernel<<<1, 512, 0, stream>>>(sm, im, cnt_s, cnt_i, iu, ju, loss);
  conv_all<<<(SPAN_F4 + IMG_F4) / 256, 256, 0, stream>>>(span, img, spbf, imgbf);
  transpose_all<<<dim3(32, 16, 5), dim3(32, 8), 0, stream>>>(Wg, W1, W2, WgT, UVBT, W1cT, W2T);
  make_z<<<R_*512/4/256, 256, 0, stream>>>(span, iu, ju, b3, Zbf, text);

  // M / loss path
  gemm_sgbf<<<dim3(8, 32), 256, 0, stream>>>(spbf, WgT, SGbf);
  batched_m_mfma<<<B_, 256, 0, stream>>>(SGbf, imgbf, sm, Mout, Msum, Mtot);
  sent_kernel<<<B_, B_, 0, stream>>>(Msum, im, cnt_s, cnt_i, Mtot, sent);
  lse_loss<<<B_, B_, 0, stream>>>(sent, loss);

  // text path
  gemm_uv<<<dim3(8, 32), 256, 0, stream>>>(spbf, UVBT, UVbf);
  gemm_zh<<<R_/64, 256, 0, stream>>>(Zbf, W1cT, W2T, UVbf, b1, b2, W3, iu, ju, text);
}

// Round 6
// 287.057 us; speedup vs baseline: 1.6275x; 1.6275x over previous
//
#include <hip/hip_runtime.h>

#define B_  128
#define N_  32
#define L_  36
#define DS  512
#define DV  1024
#define H_  512
#define P_  496
#define R_  63488      // B_*P_

typedef __attribute__((ext_vector_type(8))) short bf16x8;
typedef __attribute__((ext_vector_type(4))) float f32x4;

__device__ __forceinline__ ushort f2bf(float x){
  unsigned u = __builtin_bit_cast(unsigned, x);
  return (ushort)((u + 0x7FFFu + ((u >> 16) & 1u)) >> 16);
}
__device__ __forceinline__ float bf2f(ushort u){
  unsigned v = ((unsigned)u) << 16;
  return __builtin_bit_cast(float, v);
}

__device__ __forceinline__ void gload16(const void* g, void* l){
  __builtin_amdgcn_global_load_lds((const __attribute__((address_space(1))) unsigned*)g,
                                   (__attribute__((address_space(3))) unsigned*)l, 16, 0, 0);
}

// ---------- wave helpers ----------
__device__ __forceinline__ float wave_sum(float v){
  #pragma unroll
  for (int m = 32; m >= 1; m >>= 1) v += __shfl_xor(v, m);
  return v;
}
__device__ __forceinline__ float wave_max(float v){
  #pragma unroll
  for (int m = 32; m >= 1; m >>= 1) v = fmaxf(v, __shfl_xor(v, m));
  return v;
}

// ---------- merged setup: pair table + mask counts + loss zero ----------
__global__ void setup_kernel(const float* __restrict__ sm, const float* __restrict__ im,
                             float* cnt_s, float* cnt_i, int* iu, int* ju, float* loss){
  int t = threadIdx.x;  // 512
  if (t < P_){
    int i = 0, rem = t, cnt = N_ - 1;
    while (rem >= cnt){ rem -= cnt; ++i; --cnt; }
    iu[t] = i; ju[t] = i + 1 + rem;
  }
  if (t < B_){
    float s = 0.f;
    for (int n = 0; n < N_; ++n) s += sm[t*N_ + n];
    cnt_s[t] = s;
  } else if (t < 2*B_){
    int j = t - B_;
    float s = 0.f;
    for (int l = 0; l < L_; ++l) s += im[j*L_ + l];
    cnt_i[j] = s;
  }
  if (t == 0) loss[0] = 0.f;
}

// ---------- merged conversions: span + img -> bf16 ----------
#define SPAN_F4 524288        // 4096*512/4
#define IMG_F4  1179648       // 128*36*1024/4
__global__ void conv_all(const float* __restrict__ span, const float* __restrict__ img,
                         ushort* __restrict__ spbf, ushort* __restrict__ imgbf){
  int idx = blockIdx.x * 256 + threadIdx.x;
  const float* src; ushort* dst; int k;
  if (idx < SPAN_F4){ src = span; dst = spbf; k = idx; }
  else              { src = img;  dst = imgbf; k = idx - SPAN_F4; }
  float4 v = *(const float4*)&src[(size_t)k * 4];
  ushort4 o; o.x = f2bf(v.x); o.y = f2bf(v.y); o.z = f2bf(v.z); o.w = f2bf(v.w);
  *(ushort4*)&dst[(size_t)k * 4] = o;
}

// ---------- merged weight transposes (Wg, W1 x3, W2) ----------
__global__ void transpose_all(const float* __restrict__ Wg, const float* __restrict__ W1,
                              const float* __restrict__ W2, ushort* __restrict__ WgT,
                              ushort* __restrict__ UVBT, ushort* __restrict__ W1cT,
                              ushort* __restrict__ W2T){
  const int z = blockIdx.z;
  const float* src; ushort* dst; int N;
  if      (z == 0){ src = Wg;            dst = WgT;            N = 1024; }
  else if (z == 1){ src = W1;            dst = UVBT;           N = 512;  }
  else if (z == 2){ src = W1 + 512*512;  dst = UVBT + 512*512; N = 512;  }
  else if (z == 3){ src = W1 + 1024*512; dst = W1cT;           N = 512;  }
  else            { src = W2;            dst = W2T;            N = 512;  }
  if (blockIdx.x * 32 >= N) return;
  __shared__ float tile[32][33];
  int n0 = blockIdx.x * 32, k0 = blockIdx.y * 32;
  int x = threadIdx.x, y = threadIdx.y;   // 32 x 8
  #pragma unroll
  for (int i = 0; i < 4; ++i) tile[y + 8*i][x] = src[(k0 + y + 8*i) * N + n0 + x];
  __syncthreads();
  #pragma unroll
  for (int i = 0; i < 4; ++i) dst[(n0 + y + 8*i) * 512 + k0 + x] = f2bf(tile[x][y + 8*i]);
}

// Z[r][k] = spbf[b,i,k]*spbf[b,j,k] bf16 (8 elems/thread); also text[r] = b3
__global__ void make_z(const ushort* __restrict__ spbf, const int* __restrict__ iu,
                       const int* __restrict__ ju, const float* __restrict__ b3,
                       ushort* __restrict__ Z, float* __restrict__ text){
  int idx = blockIdx.x * 256 + threadIdx.x;    // 8 elems each; R_*512/8 total
  if (idx < R_) text[idx] = b3[0];
  int r = idx >> 6;
  int k = (idx & 63) << 3;
  int b = r / P_, p = r - b * P_;
  bf16x8 x = *(const bf16x8*)&spbf[(b * N_ + iu[p]) * 512 + k];
  bf16x8 y = *(const bf16x8*)&spbf[(b * N_ + ju[p]) * 512 + k];
  bf16x8 o;
  #pragma unroll
  for (int e = 0; e < 8; ++e)
    o[e] = (short)f2bf(bf2f((ushort)x[e]) * bf2f((ushort)y[e]));
  *(bf16x8*)&Z[(size_t)r * 512 + k] = o;
}

// ---------- shared bf16 MFMA mainloop (LDS-staged, 128x128 tile, BK=32) ----------
__device__ __forceinline__ void mma_mainloop(const ushort* __restrict__ A,
                                             const ushort* __restrict__ BT,
                                             size_t m0, int n0,
                                             ushort* sA, ushort* sB, f32x4 acc[4][4]){
  const int tid = threadIdx.x, wid = tid >> 6, lane = tid & 63;
  const int wm = (wid >> 1) * 64, wn = (wid & 1) * 64;
  const int quad = lane >> 4, fm = lane & 15;
  const char* gA = (const char*)A + (m0 + (size_t)(wid * 32 + (lane >> 2))) * 1024 + (lane & 3) * 16;
  const char* gB = (const char*)BT + ((size_t)n0 + wid * 32 + (lane >> 2)) * 1024 + (lane & 3) * 16;
  ushort* lA = sA + wid * 32 * 32;
  ushort* lB = sB + wid * 32 * 32;
  #pragma unroll 1
  for (int ks = 0; ks < 16; ++ks){
    gload16(gA,             lA);
    gload16(gA + 16 * 1024, lA + 16 * 32);
    gload16(gB,             lB);
    gload16(gB + 16 * 1024, lB + 16 * 32);
    __syncthreads();
    bf16x8 af[4], bg[4];
    #pragma unroll
    for (int i = 0; i < 4; ++i){
      af[i] = *(const bf16x8*)&sA[(wm + i * 16 + fm) * 32 + quad * 8];
      bg[i] = *(const bf16x8*)&sB[(wn + i * 16 + fm) * 32 + quad * 8];
    }
    #pragma unroll
    for (int i = 0; i < 4; ++i)
      #pragma unroll
      for (int j = 0; j < 4; ++j)
        acc[i][j] = __builtin_amdgcn_mfma_f32_16x16x32_bf16(af[i], bg[j], acc[i][j], 0, 0, 0);
    __syncthreads();
    gA += 64; gB += 64;
  }
}

// Fused span GEMMs: [SGbf | UVbf] = spbf @ [WgT ; UVBT]  (4096 x 2048), bf16 out
__global__ __launch_bounds__(256) void gemm_span2(const ushort* __restrict__ A,
                                                  const ushort* __restrict__ BT2,
                                                  ushort* __restrict__ SG,
                                                  ushort* __restrict__ UV){
  __shared__ ushort sA[4096], sB[4096];
  f32x4 acc[4][4] = {};
  size_t m0 = (size_t)blockIdx.y * 128; int ng = blockIdx.x * 128;
  mma_mainloop(A, BT2, m0, ng, sA, sB, acc);
  const int tid = threadIdx.x, wid = tid >> 6, lane = tid & 63;
  const int wm = (wid >> 1) * 64, wn = (wid & 1) * 64, quad = lane >> 4, fm = lane & 15;
  ushort* C = (ng < 1024) ? SG : UV;
  const int nbase = (ng < 1024) ? ng : (ng - 1024);
  #pragma unroll
  for (int i = 0; i < 4; ++i)
    #pragma unroll
    for (int r = 0; r < 4; ++r){
      size_t row = m0 + wm + i * 16 + quad * 4 + r;
      #pragma unroll
      for (int j = 0; j < 4; ++j){
        int col = nbase + wn + j * 16 + fm;
        C[row * 1024 + col] = f2bf(acc[i][j][r]);
      }
    }
}

// M[b] = SGbf[b] @ imgbf[b]^T; also Msum[b,:] and Mtot[b]
__global__ __launch_bounds__(256) void batched_m_mfma(const ushort* __restrict__ SGbf,
                                                      const ushort* __restrict__ imgbf,
                                                      const float* __restrict__ sm,
                                                      float* __restrict__ Mout,
                                                      float* __restrict__ Msum,
                                                      float* __restrict__ Mtot){
  const int b = blockIdx.x;
  const int tid = threadIdx.x, wid = tid >> 6, lane = tid & 63;
  const int quad = lane >> 4, fm = lane & 15;
  __shared__ float red[4][32][48];
  __shared__ float shr[4];
  f32x4 acc[2][3] = {};
  const int wk = wid * 256;              // K-quarter base
  const ushort* Ab = SGbf + (size_t)b * 32 * 1024;
  const ushort* Bb = imgbf + (size_t)b * 36 * 1024;
  #pragma unroll
  for (int ks = 0; ks < 8; ++ks){
    const int k = wk + ks * 32 + quad * 8;
    bf16x8 af[2], bg[3];
    af[0] = *(const bf16x8*)&Ab[(0*16 + fm) * 1024 + k];
    af[1] = *(const bf16x8*)&Ab[(1*16 + fm) * 1024 + k];
    bg[0] = *(const bf16x8*)&Bb[(0*16 + fm) * 1024 + k];
    bg[1] = *(const bf16x8*)&Bb[(1*16 + fm) * 1024 + k];
    bg[2] = *(const bf16x8*)&Bb[(2*16 + fm) * 1024 + k];  // rows 36..47 slack
    #pragma unroll
    for (int i = 0; i < 2; ++i)
      #pragma unroll
      for (int j = 0; j < 3; ++j)
        acc[i][j] = __builtin_amdgcn_mfma_f32_16x16x32_bf16(af[i], bg[j], acc[i][j], 0, 0, 0);
  }
  #pragma unroll
  for (int i = 0; i < 2; ++i)
    #pragma unroll
    for (int j = 0; j < 3; ++j)
      #pragma unroll
      for (int r = 0; r < 4; ++r)
        red[wid][i*16 + quad*4 + r][j*16 + fm] = acc[i][j][r];
  __syncthreads();
  float tot = 0.f;
  #pragma unroll
  for (int q = 0; q < 5; ++q){
    int out = tid + 256 * q;
    if (out < N_*L_){
      int n = out / L_, l = out - n * L_;
      float v = red[0][n][l] + red[1][n][l] + red[2][n][l] + red[3][n][l];
      Mout[b * (N_*L_) + out] = v;
      tot += v;
    }
  }
  tot = wave_sum(tot);
  if (lane == 0) shr[wid] = tot;
  __syncthreads();
  if (tid == 0) Mtot[b] = shr[0] + shr[1] + shr[2] + shr[3];
  if (tid < L_){
    float s = 0.f;
    for (int n = 0; n < N_; ++n){
      float mv = red[0][n][tid] + red[1][n][tid] + red[2][n][tid] + red[3][n][tid];
      s += mv * sm[b*N_ + n];
    }
    Msum[b*L_ + tid] = s;
  }
}

__global__ void sent_kernel(const float* __restrict__ Msum, const float* __restrict__ im,
                            const float* __restrict__ cnt_s, const float* __restrict__ cnt_i,
                            const float* __restrict__ Mtot, float* __restrict__ sent){
  const int i = blockIdx.x, j = threadIdx.x;  // 128 threads
  float s = 0.f;
  for (int l = 0; l < L_; ++l) s += Msum[i*L_ + l] * im[j*L_ + l];
  const float d = cnt_s[i] * cnt_i[j];
  sent[i*B_ + j] = (d != 0.f) ? (s / d) : (Mtot[i] * (1.f/(float)(N_*L_)));
}

// per-row/col logsumexp + direct loss accumulation (atomic)
__global__ void lse_loss(const float* __restrict__ sent, float* __restrict__ out){
  const int i = blockIdx.x, t = threadIdx.x;  // 128 threads = 2 waves
  const int wid = t >> 6, lane = t & 63;
  __shared__ float sh[2];
  const float vr = sent[i*B_ + t];
  const float vc = sent[t*B_ + i];

  float m = wave_max(vr);
  if (lane == 0) sh[wid] = m;
  __syncthreads();
  const float mr = fmaxf(sh[0], sh[1]);
  __syncthreads();
  float e = wave_sum(expf(vr - mr));
  if (lane == 0) sh[wid] = e;
  __syncthreads();
  const float ser = sh[0] + sh[1];
  __syncthreads();
  float rs = wave_sum(vr);
  if (lane == 0) sh[wid] = rs;
  __syncthreads();
  const float rst = sh[0] + sh[1];
  __syncthreads();
  float mc0 = wave_max(vc);
  if (lane == 0) sh[wid] = mc0;
  __syncthreads();
  const float mc = fmaxf(sh[0], sh[1]);
  __syncthreads();
  float ec = wave_sum(expf(vc - mc));
  if (lane == 0) sh[wid] = ec;
  __syncthreads();
  const float sec = sh[0] + sh[1];
  if (t == 0){
    float contrib = (mr + logf(ser)) + (mc + logf(sec)) - 2.f * rst / (float)B_;
    atomicAdd(out, contrib);
  }
}

// ---------- FUSED text path (R4 structure: LDS-staged K-loops, sH XOR-swizzled) ----------
// 64 rows/block. Phase 1: h1 = relu(Z@W1c + U + V + b1) -> sH. Phase 2: text += relu(sH@W2+b2).W3
// sH layout: element (row, col) at sH[row*512 + (col ^ ((row&7)*8))] — spreads the 16 fm-rows
// of a phase-2 ds_read_b128 across all 32 banks (2-way residual = free).
__global__ __launch_bounds__(256, 2) void gemm_zh(const ushort* __restrict__ Z,
                                                  const ushort* __restrict__ W1cT,
                                                  const ushort* __restrict__ W2T,
                                                  const ushort* __restrict__ UV,
                                                  const float* __restrict__ b1,
                                                  const float* __restrict__ b2,
                                                  const float* __restrict__ W3,
                                                  const int* __restrict__ iu,
                                                  const int* __restrict__ ju,
                                                  float* __restrict__ text){
  extern __shared__ ushort smem[];
  ushort* sH = smem;                 // 64 x 512, XOR-swizzled
  ushort* sA = smem + 64 * 512;      // 64 x 32
  ushort* sB = sA + 64 * 32;         // 128 x 32
  const int tid = threadIdx.x, wid = tid >> 6, lane = tid & 63;
  const int wm = (wid >> 1) * 32, wn = (wid & 1) * 64;
  const int quad = lane >> 4, fm = lane & 15;
  const int m0 = blockIdx.x * 64;

  int grow[8], uoff[8], voff[8];
  #pragma unroll
  for (int i = 0; i < 2; ++i)
    #pragma unroll
    for (int r = 0; r < 4; ++r){
      int row = m0 + wm + i * 16 + quad * 4 + r;
      grow[i*4+r] = row;
      int b = row / P_, p = row - b * P_;
      uoff[i*4+r] = (b * N_ + iu[p]) * 1024;
      voff[i*4+r] = (b * N_ + ju[p]) * 1024 + 512;
    }

  // ---- phase 1: h1 tile -> sH ----
  const char* gA0 = (const char*)Z + ((size_t)(m0 + wid * 16 + (lane >> 2))) * 1024 + (lane & 3) * 16;
  ushort* lA = sA + wid * 16 * 32;
  ushort* lB = sB + wid * 32 * 32;
  for (int n0 = 0; n0 < 512; n0 += 128){
    f32x4 acc[2][4] = {};
    const char* gA = gA0;
    const char* gB = (const char*)W1cT + ((size_t)(n0 + wid * 32 + (lane >> 2))) * 1024 + (lane & 3) * 16;
    #pragma unroll 1
    for (int ks = 0; ks < 16; ++ks){
      gload16(gA, lA);
      gload16(gB,             lB);
      gload16(gB + 16 * 1024, lB + 16 * 32);
      __syncthreads();
      bf16x8 af[2], bg[4];
      #pragma unroll
      for (int i = 0; i < 2; ++i)
        af[i] = *(const bf16x8*)&sA[(wm + i * 16 + fm) * 32 + quad * 8];
      #pragma unroll
      for (int j = 0; j < 4; ++j)
        bg[j] = *(const bf16x8*)&sB[(wn + j * 16 + fm) * 32 + quad * 8];
      #pragma unroll
      for (int i = 0; i < 2; ++i)
        #pragma unroll
        for (int j = 0; j < 4; ++j)
          acc[i][j] = __builtin_amdgcn_mfma_f32_16x16x32_bf16(af[i], bg[j], acc[i][j], 0, 0, 0);
      __syncthreads();
      gA += 64; gB += 64;
    }
    // epilogue -> sH (swizzled); sH disjoint from sA/sB
    #pragma unroll
    for (int i = 0; i < 2; ++i)
      #pragma unroll
      for (int r = 0; r < 4; ++r){
        const int e = i*4 + r;
        const int lrow = wm + i * 16 + quad * 4 + r;
        const int swz = (lrow & 7) * 8;
        #pragma unroll
        for (int j = 0; j < 4; ++j){
          int col = n0 + wn + j * 16 + fm;
          float h = acc[i][j][r] + bf2f(UV[uoff[e] + col]) + bf2f(UV[voff[e] + col]) + b1[col];
          sH[lrow * 512 + (col ^ swz)] = f2bf(fmaxf(h, 0.f));
        }
      }
  }
  __syncthreads();

  // ---- phase 2: text += relu(sH @ W2 + b2) . W3 ----
  const int swzr = (fm & 7) * 8;    // (row&7)*8 for row = wm + i*16 + fm
  float srow[8] = {};
  for (int n0 = 0; n0 < 512; n0 += 128){
    f32x4 acc[2][4] = {};
    const char* gB = (const char*)W2T + ((size_t)(n0 + wid * 32 + (lane >> 2))) * 1024 + (lane & 3) * 16;
    #pragma unroll 1
    for (int ks = 0; ks < 16; ++ks){
      gload16(gB,             lB);
      gload16(gB + 16 * 1024, lB + 16 * 32);
      __syncthreads();
      bf16x8 af[2], bg[4];
      #pragma unroll
      for (int i = 0; i < 2; ++i)
        af[i] = *(const bf16x8*)&sH[(wm + i * 16 + fm) * 512 + ((ks * 32 + quad * 8) ^ swzr)];
      #pragma unroll
      for (int j = 0; j < 4; ++j)
        bg[j] = *(const bf16x8*)&sB[(wn + j * 16 + fm) * 32 + quad * 8];
      #pragma unroll
      for (int i = 0; i < 2; ++i)
        #pragma unroll
        for (int j = 0; j < 4; ++j)
          acc[i][j] = __builtin_amdgcn_mfma_f32_16x16x32_bf16(af[i], bg[j], acc[i][j], 0, 0, 0);
      __syncthreads();
      gB += 64;
    }
    #pragma unroll
    for (int i = 0; i < 2; ++i)
      #pragma unroll
      for (int r = 0; r < 4; ++r){
        float s = srow[i*4+r];
        #pragma unroll
        for (int j = 0; j < 4; ++j){
          int col = n0 + wn + j * 16 + fm;
          float h = fmaxf(acc[i][j][r] + b2[col], 0.f);
          s = fmaf(h, W3[col], s);
        }
        srow[i*4+r] = s;
      }
  }
  #pragma unroll
  for (int e = 0; e < 8; ++e){
    float s = srow[e];
    s += __shfl_xor(s, 1); s += __shfl_xor(s, 2); s += __shfl_xor(s, 4); s += __shfl_xor(s, 8);
    if (fm == 0) atomicAdd(&text[grow[e]], s);
  }
}

extern "C" void kernel_launch(void* const* d_in, const int* in_sizes, int n_in,
                              void* d_out, int out_size, void* d_ws, size_t ws_size,
                              hipStream_t stream) {
  const float* span = (const float*)d_in[0];
  const float* img  = (const float*)d_in[1];
  const float* sm   = (const float*)d_in[2];
  const float* im   = (const float*)d_in[3];
  const float* Wg   = (const float*)d_in[4];
  const float* W1   = (const float*)d_in[5];
  const float* b1   = (const float*)d_in[6];
  const float* W2   = (const float*)d_in[7];
  const float* b2   = (const float*)d_in[8];
  const float* W3   = (const float*)d_in[9];
  const float* b3   = (const float*)d_in[10];

  float* out  = (float*)d_out;
  float* loss = out;
  float* Mout = out + 1;
  float* text = out + 1 + B_*N_*L_;

  ushort* wsu  = (ushort*)d_ws;
  ushort* Zbf  = wsu;                          // R_*512
  ushort* UVbf = Zbf + (size_t)R_*512;         // 4096*1024
  ushort* SGbf = UVbf + 4096*1024;             // 4096*1024
  ushort* spbf = SGbf + 4096*1024;             // 4096*512
  ushort* imgbf= spbf + 4096*512;              // (128*36+12)*1024
  ushort* BT2  = imgbf + (size_t)(B_*L_ + 12)*1024; // WgT (1024*512) then UVBT (1024*512)
  ushort* WgT  = BT2;
  ushort* UVBT = BT2 + 1024*512;
  ushort* W1cT = UVBT + 1024*512;              // 512*512
  ushort* W2T  = W1cT + 512*512;               // 512*512
  float* Msum  = (float*)(W2T + 512*512);      // 4608
  float* Mtot  = Msum + B_*L_;
  float* cnt_s = Mtot + B_;
  float* cnt_i = cnt_s + B_;
  float* sent  = cnt_i + B_;                   // 16384
  int*   iu    = (int*)(sent + B_*B_);         // 496
  int*   ju    = iu + P_;                      // 496

  setup_kernel<<<1, 512, 0, stream>>>(sm, im, cnt_s, cnt_i, iu, ju, loss);
  conv_all<<<(SPAN_F4 + IMG_F4) / 256, 256, 0, stream>>>(span, img, spbf, imgbf);
  transpose_all<<<dim3(32, 16, 5), dim3(32, 8), 0, stream>>>(Wg, W1, W2, WgT, UVBT, W1cT, W2T);
  make_z<<<R_*512/8/256, 256, 0, stream>>>(spbf, iu, ju, b3, Zbf, text);

  // span GEMMs (fused): SGbf and UVbf
  gemm_span2<<<dim3(16, 32), 256, 0, stream>>>(spbf, BT2, SGbf, UVbf);

  // M / loss path
  batched_m_mfma<<<B_, 256, 0, stream>>>(SGbf, imgbf, sm, Mout, Msum, Mtot);
  sent_kernel<<<B_, B_, 0, stream>>>(Msum, im, cnt_s, cnt_i, Mtot, sent);
  lse_loss<<<B_, B_, 0, stream>>>(sent, loss);

  // text path
  gemm_zh<<<R_/64, 256, (64*512 + 64*32 + 128*32) * sizeof(ushort), stream>>>(
      Zbf, W1cT, W2T, UVbf, b1, b2, W3, iu, ju, text);
}